// Round 2
// baseline (7800.850 us; speedup 1.0000x reference)
//
#include <hip/hip_runtime.h>
#include <hip/hip_bf16.h>

#define B_ 4
#define L_ 4096
#define E_ 1024
#define H_ 16
#define D_ 64
#define MLP_ 4096
#define M_ (B_*L_)
#define LK_ (L_+1)

// ---------------- generic fp32 tiled GEMM: C = A[M,K]@W[K,N] + bias, epilogue ----------------
// EPI 0: none; 2: exact gelu; 3: v + R1 + R2 (residuals)
template<int EPI>
__global__ __launch_bounds__(256)
void gemm_f32(const float* __restrict__ A, const float* __restrict__ W,
              const float* __restrict__ bias, float* __restrict__ C,
              int M, int N, int K,
              const float* __restrict__ R1, const float* __restrict__ R2)
{
    __shared__ float As[32][68];   // A tile transposed [BK][BM+pad]
    __shared__ float Bs[32][64];
    const int tid = threadIdx.x;
    const int tx = tid & 15, ty = tid >> 4;
    const int bm = blockIdx.y, bn = blockIdx.x;
    const float* Ab = A + (size_t)bm*64*K;
    const float* Wb = W + bn*64;
    float acc[4][4] = {};
    const int ar = (tid*8) >> 5;      // 0..63
    const int ac = (tid*8) & 31;      // multiple of 8
    const int br = (tid*8) >> 6;      // 0..31
    const int bc = (tid*8) & 63;      // multiple of 8
    for (int kt = 0; kt < K; kt += 32) {
        float4 a0 = *(const float4*)(Ab + (size_t)ar*K + kt + ac);
        float4 a1 = *(const float4*)(Ab + (size_t)ar*K + kt + ac + 4);
        float4 b0 = *(const float4*)(Wb + (size_t)(kt+br)*N + bc);
        float4 b1 = *(const float4*)(Wb + (size_t)(kt+br)*N + bc + 4);
        As[ac+0][ar]=a0.x; As[ac+1][ar]=a0.y; As[ac+2][ar]=a0.z; As[ac+3][ar]=a0.w;
        As[ac+4][ar]=a1.x; As[ac+5][ar]=a1.y; As[ac+6][ar]=a1.z; As[ac+7][ar]=a1.w;
        *(float4*)&Bs[br][bc]   = b0;
        *(float4*)&Bs[br][bc+4] = b1;
        __syncthreads();
        #pragma unroll
        for (int kk = 0; kk < 32; ++kk) {
            float4 a4 = *(const float4*)&As[kk][ty*4];
            float4 b4 = *(const float4*)&Bs[kk][tx*4];
            float av[4] = {a4.x,a4.y,a4.z,a4.w};
            float bv[4] = {b4.x,b4.y,b4.z,b4.w};
            #pragma unroll
            for (int i=0;i<4;++i)
                #pragma unroll
                for (int j=0;j<4;++j)
                    acc[i][j] = fmaf(av[i], bv[j], acc[i][j]);
        }
        __syncthreads();
    }
    #pragma unroll
    for (int i=0;i<4;++i) {
        int row = bm*64 + ty*4 + i;
        #pragma unroll
        for (int j=0;j<4;++j) {
            int col = bn*64 + tx*4 + j;
            float v = acc[i][j] + bias[col];
            if (EPI==2) v = 0.5f*v*(1.0f + erff(v*0.70710678118654752f));
            if (EPI==3) v += R1[(size_t)row*N+col] + R2[(size_t)row*N+col];
            C[(size_t)row*N+col] = v;
        }
    }
}

// ---------------- row LayerNorm over E=1024, eps=1e-5 ----------------
__global__ __launch_bounds__(256)
void layernorm_rows(const float* __restrict__ in, const float* __restrict__ g,
                    const float* __restrict__ bta, float* __restrict__ out)
{
    __shared__ float red[8];
    const int row = blockIdx.x;
    const float* x = in + (size_t)row*E_;
    float v[4];
    float s = 0.f, s2 = 0.f;
    #pragma unroll
    for (int i=0;i<4;++i){ v[i] = x[threadIdx.x + i*256]; s += v[i]; s2 += v[i]*v[i]; }
    #pragma unroll
    for (int o=32;o;o>>=1){ s += __shfl_xor(s,o); s2 += __shfl_xor(s2,o); }
    int w = threadIdx.x >> 6;
    if ((threadIdx.x & 63) == 0){ red[w] = s; red[4+w] = s2; }
    __syncthreads();
    s  = red[0]+red[1]+red[2]+red[3];
    s2 = red[4]+red[5]+red[6]+red[7];
    float mu  = s * (1.0f/E_);
    float var = s2 * (1.0f/E_) - mu*mu;
    float rs  = rsqrtf(var + 1e-5f);
    float* o_ = out + (size_t)row*E_;
    #pragma unroll
    for (int i=0;i<4;++i){
        int c = threadIdx.x + i*256;
        o_[c] = (v[i]-mu)*rs*g[c] + bta[c];
    }
}

// ---------------- qg partial sums: qg[b,e] += sum over 64 l's ----------------
__global__ __launch_bounds__(1024)
void qg_partial(const float* __restrict__ Q, float* __restrict__ qg)
{
    int b = blockIdx.x >> 6;
    int c = blockIdx.x & 63;
    int e = threadIdx.x;
    float s = 0.f;
    const float* p = Q + ((size_t)b*L_ + c*64)*E_ + e;
    for (int l=0; l<64; ++l) s += p[(size_t)l*E_];
    atomicAdd(&qg[b*E_ + e], s);
}

// ---------------- scores -> softmax -> alpha (incl. zero token at index 0) ----------------
__global__ __launch_bounds__(256)
void rala_alpha(const float* __restrict__ K, const float* __restrict__ qg,
                float* __restrict__ alpha)
{
    __shared__ float sc[L_];     // 16 KiB
    __shared__ float qs[D_];
    __shared__ float red[8];
    int bh = blockIdx.x; int b = bh >> 4, h = bh & 15;
    int tid = threadIdx.x;
    if (tid < D_) qs[tid] = qg[b*E_ + h*D_ + tid] * (1.0f/(L_ * 8.0f)); // mean/L and /sqrt(D)=8
    __syncthreads();
    int wv = tid >> 6, lane = tid & 63;
    const float* Kb = K + (size_t)b*L_*E_ + h*D_ + lane;
    for (int l = wv; l < L_; l += 4) {
        float v = Kb[(size_t)l*E_] * qs[lane];
        #pragma unroll
        for (int o=32;o;o>>=1) v += __shfl_xor(v,o);
        if (lane==0) sc[l] = v;
    }
    __syncthreads();
    float mx = 0.f;                                  // zero-token score = 0 included
    for (int i=tid;i<L_;i+=256) mx = fmaxf(mx, sc[i]);
    #pragma unroll
    for (int o=32;o;o>>=1) mx = fmaxf(mx, __shfl_xor(mx,o));
    if (lane==0) red[wv] = mx;
    __syncthreads();
    mx = fmaxf(fmaxf(red[0],red[1]), fmaxf(red[2],red[3]));
    float sum = 0.f;
    for (int i=tid;i<L_;i+=256){ float e = expf(sc[i]-mx); sc[i]=e; sum += e; }
    #pragma unroll
    for (int o=32;o;o>>=1) sum += __shfl_xor(sum,o);
    __syncthreads();
    if (lane==0) red[4+wv] = sum;
    __syncthreads();
    float Z = red[4]+red[5]+red[6]+red[7] + expf(-mx);   // + zero token
    float scale = (float)L_ / Z;                          // softmax * Lq
    float* al = alpha + (size_t)bh*LK_;
    for (int i=tid;i<L_;i+=256) al[1+i] = sc[i]*scale;
    if (tid==0) al[0] = expf(-mx)*scale;
}

// ---------------- fused phiK GEMM + KV/Ksum accumulation ----------------
// block = (b, h, 256-row chunk). For each 64-row subtile:
//   T = K_rows @ Wphi_k[:, h*64:...] + bphi_k ; phiKs = (tanh(T)+1)*alpha_row
//   acc2[d][e] += sum_l phiKs[l][d] * V[l][e] ; ksum[d] += sum_l phiKs[l][d]
__global__ __launch_bounds__(256)
void phik_kv(const float* __restrict__ Kmat, const float* __restrict__ Vmat,
             const float* __restrict__ Wphi, const float* __restrict__ bphi,
             const float* __restrict__ alpha, float* __restrict__ KV,
             float* __restrict__ Ksum)
{
    __shared__ float As[32][68];
    __shared__ float Bs[32][64];
    __shared__ float Ps[64][68];
    __shared__ float Vs[64][68];
    const int tid = threadIdx.x;
    const int tx = tid & 15, ty = tid >> 4;
    const int h  = blockIdx.x & 15;
    const int cid = blockIdx.x >> 4;            // 0..63
    const int row0 = cid * 256;
    const int b  = row0 >> 12;                  // row0 / L_
    const int l0 = row0 & (L_-1);
    const size_t bh = (size_t)(b*H_ + h);
    const int ar = (tid*8) >> 5, ac = (tid*8) & 31;
    const int br = (tid*8) >> 6, bc = (tid*8) & 63;
    const int vr = tid >> 2,     vc = (tid & 3) * 16;
    float acc2[4][4] = {};
    float ksl = 0.f;
    for (int cc = 0; cc < 4; ++cc) {
        const float* Ab = Kmat + (size_t)(row0 + cc*64) * E_;
        float acc[4][4] = {};
        for (int kt = 0; kt < E_; kt += 32) {
            float4 a0 = *(const float4*)(Ab + (size_t)ar*E_ + kt + ac);
            float4 a1 = *(const float4*)(Ab + (size_t)ar*E_ + kt + ac + 4);
            float4 b0 = *(const float4*)(Wphi + (size_t)(kt+br)*E_ + h*64 + bc);
            float4 b1 = *(const float4*)(Wphi + (size_t)(kt+br)*E_ + h*64 + bc + 4);
            As[ac+0][ar]=a0.x; As[ac+1][ar]=a0.y; As[ac+2][ar]=a0.z; As[ac+3][ar]=a0.w;
            As[ac+4][ar]=a1.x; As[ac+5][ar]=a1.y; As[ac+6][ar]=a1.z; As[ac+7][ar]=a1.w;
            *(float4*)&Bs[br][bc]   = b0;
            *(float4*)&Bs[br][bc+4] = b1;
            __syncthreads();
            #pragma unroll
            for (int kk = 0; kk < 32; ++kk) {
                float4 a4 = *(const float4*)&As[kk][ty*4];
                float4 b4 = *(const float4*)&Bs[kk][tx*4];
                float av[4] = {a4.x,a4.y,a4.z,a4.w};
                float bv[4] = {b4.x,b4.y,b4.z,b4.w};
                #pragma unroll
                for (int i=0;i<4;++i)
                    #pragma unroll
                    for (int j=0;j<4;++j)
                        acc[i][j] = fmaf(av[i], bv[j], acc[i][j]);
            }
            __syncthreads();
        }
        // load V tile + write phiKs (scaled) to Ps
        {
            const float* Vb = Vmat + (size_t)(row0 + cc*64) * E_ + h*64;
            *(float4*)&Vs[vr][vc]    = *(const float4*)(Vb + (size_t)vr*E_ + vc);
            *(float4*)&Vs[vr][vc+4]  = *(const float4*)(Vb + (size_t)vr*E_ + vc + 4);
            *(float4*)&Vs[vr][vc+8]  = *(const float4*)(Vb + (size_t)vr*E_ + vc + 8);
            *(float4*)&Vs[vr][vc+12] = *(const float4*)(Vb + (size_t)vr*E_ + vc + 12);
            #pragma unroll
            for (int i=0;i<4;++i){
                int l = ty*4 + i;
                float a = alpha[bh*LK_ + 1 + l0 + cc*64 + l];
                #pragma unroll
                for (int j=0;j<4;++j){
                    float v = tanhf(acc[i][j] + bphi[h*64 + tx*4 + j]) + 1.0f;
                    Ps[l][tx*4+j] = v * a;
                }
            }
        }
        __syncthreads();
        // acc2[d][e] += sum_l Ps[l][d]*Vs[l][e]  (d=ty*4+i, e=tx*4+j)
        #pragma unroll
        for (int lr=0; lr<64; ++lr){
            float4 p4 = *(const float4*)&Ps[lr][ty*4];
            float4 v4 = *(const float4*)&Vs[lr][tx*4];
            float pv[4]={p4.x,p4.y,p4.z,p4.w}, vv[4]={v4.x,v4.y,v4.z,v4.w};
            #pragma unroll
            for (int i=0;i<4;++i)
                #pragma unroll
                for (int j=0;j<4;++j)
                    acc2[i][j] = fmaf(pv[i], vv[j], acc2[i][j]);
        }
        if (tid < 64){
            float t = 0.f;
            #pragma unroll
            for (int lr=0; lr<64; ++lr) t += Ps[lr][tid];
            ksl += t;
        }
        __syncthreads();
    }
    #pragma unroll
    for (int i=0;i<4;++i)
        #pragma unroll
        for (int j=0;j<4;++j)
            atomicAdd(&KV[(bh*D_ + ty*4+i)*D_ + tx*4+j], acc2[i][j]);
    if (tid < 64) atomicAdd(&Ksum[bh*D_ + tid], ksl);
}

// zero-token contribution to K_sum: (tanh(bphi_k)+1) * alpha0
__global__ void ksum_zero(const float* __restrict__ bphi_k,
                          const float* __restrict__ alpha, float* __restrict__ Ksum)
{
    int bh = blockIdx.x; int h = bh & 15; int d = threadIdx.x;
    float a0 = alpha[(size_t)bh*LK_];
    Ksum[(size_t)bh*D_ + d] += (tanhf(bphi_k[h*D_ + d]) + 1.0f) * a0;
}

// ---------------- fused phiQ GEMM + attn = (phiQ@KV)/(phiQ.Ksum+eps) ----------------
__global__ __launch_bounds__(256)
void phiq_attn(const float* __restrict__ Qmat, const float* __restrict__ Wphi,
               const float* __restrict__ bphi, const float* __restrict__ KV,
               const float* __restrict__ Ksum, float* __restrict__ attn)
{
    __shared__ float As[32][68];
    __shared__ float Bs[32][64];
    __shared__ float Ps[64][68];
    __shared__ float KVs[64][68];
    __shared__ float Ks_[64];
    const int tid = threadIdx.x;
    const int tx = tid & 15, ty = tid >> 4;
    const int h  = blockIdx.x & 15;
    const int rc = blockIdx.x >> 4;            // 0..255
    const int row0 = rc * 64;
    const int b  = row0 >> 12;
    const size_t bh = (size_t)(b*H_ + h);
    const int ar = (tid*8) >> 5, ac = (tid*8) & 31;
    const int br = (tid*8) >> 6, bc = (tid*8) & 63;
    const int vr = tid >> 2,     vc = (tid & 3) * 16;
    // stage KV_h and Ksum_h
    {
        const float* kvb = KV + bh*D_*D_;
        *(float4*)&KVs[vr][vc]    = *(const float4*)(kvb + vr*64 + vc);
        *(float4*)&KVs[vr][vc+4]  = *(const float4*)(kvb + vr*64 + vc + 4);
        *(float4*)&KVs[vr][vc+8]  = *(const float4*)(kvb + vr*64 + vc + 8);
        *(float4*)&KVs[vr][vc+12] = *(const float4*)(kvb + vr*64 + vc + 12);
        if (tid < 64) Ks_[tid] = Ksum[bh*D_ + tid];
    }
    const float* Ab = Qmat + (size_t)row0 * E_;
    float acc[4][4] = {};
    for (int kt = 0; kt < E_; kt += 32) {
        float4 a0 = *(const float4*)(Ab + (size_t)ar*E_ + kt + ac);
        float4 a1 = *(const float4*)(Ab + (size_t)ar*E_ + kt + ac + 4);
        float4 b0 = *(const float4*)(Wphi + (size_t)(kt+br)*E_ + h*64 + bc);
        float4 b1 = *(const float4*)(Wphi + (size_t)(kt+br)*E_ + h*64 + bc + 4);
        As[ac+0][ar]=a0.x; As[ac+1][ar]=a0.y; As[ac+2][ar]=a0.z; As[ac+3][ar]=a0.w;
        As[ac+4][ar]=a1.x; As[ac+5][ar]=a1.y; As[ac+6][ar]=a1.z; As[ac+7][ar]=a1.w;
        *(float4*)&Bs[br][bc]   = b0;
        *(float4*)&Bs[br][bc+4] = b1;
        __syncthreads();
        #pragma unroll
        for (int kk = 0; kk < 32; ++kk) {
            float4 a4 = *(const float4*)&As[kk][ty*4];
            float4 b4 = *(const float4*)&Bs[kk][tx*4];
            float av[4] = {a4.x,a4.y,a4.z,a4.w};
            float bv[4] = {b4.x,b4.y,b4.z,b4.w};
            #pragma unroll
            for (int i=0;i<4;++i)
                #pragma unroll
                for (int j=0;j<4;++j)
                    acc[i][j] = fmaf(av[i], bv[j], acc[i][j]);
        }
        __syncthreads();
    }
    // phiQ tile to shared
    #pragma unroll
    for (int i=0;i<4;++i)
        #pragma unroll
        for (int j=0;j<4;++j)
            Ps[ty*4+i][tx*4+j] = tanhf(acc[i][j] + bphi[h*64 + tx*4 + j]) + 1.0f;
    __syncthreads();
    // num[l][e] = sum_d Ps[l][d]*KVs[d][e]; den[l] = sum_d Ps[l][d]*Ks_[d]
    float num[4][4] = {};
    float den[4] = {};
    for (int d=0; d<64; ++d){
        float kd = Ks_[d];
        float4 kv4 = *(const float4*)&KVs[d][tx*4];
        float kvv[4] = {kv4.x,kv4.y,kv4.z,kv4.w};
        #pragma unroll
        for (int i=0;i<4;++i){
            float q = Ps[ty*4+i][d];
            den[i] = fmaf(q, kd, den[i]);
            #pragma unroll
            for (int j=0;j<4;++j)
                num[i][j] = fmaf(q, kvv[j], num[i][j]);
        }
    }
    #pragma unroll
    for (int i=0;i<4;++i){
        float r = 1.0f / (den[i] + 1e-6f);
        #pragma unroll
        for (int j=0;j<4;++j)
            attn[(size_t)(row0 + ty*4 + i)*E_ + h*64 + tx*4 + j] = num[i][j] * r;
    }
}

// ---------------- grouped conv (k=5,pad=2,groups=H) + gated residual ----------------
__global__ __launch_bounds__(256)
void conv_residual(const float* __restrict__ attn, const float* __restrict__ conv_w,
                   const float* __restrict__ conv_b, const float* __restrict__ gamma_p,
                   float* __restrict__ out)
{
    __shared__ float As_[68][65];      // rows lc*64-2 .. lc*64+65, d
    __shared__ float Ws_[64][81];      // e_local x (16 d x 5 t), padded
    int blk = blockIdx.x;
    int lc = blk & 63; int h = (blk>>6) & 15; int b = blk >> 10;
    int tid = threadIdx.x;
    int tx = tid & 15, ty = tid >> 4;
    for (int i=tid; i<68*64; i+=256){
        int r = i>>6, cc = i&63;
        int l = lc*64 - 2 + r;
        As_[r][cc] = (l>=0 && l<L_) ? attn[((size_t)b*L_+l)*E_ + h*D_ + cc] : 0.f;
    }
    int e0 = tx*4, l0 = ty*4;
    float acc[4][4] = {};
    for (int dc=0; dc<4; ++dc){
        __syncthreads();
        for (int i=tid; i<64*80; i+=256){
            int ee = i/80, rem = i%80;
            Ws_[ee][rem] = conv_w[((size_t)(h*D_+ee))*320 + dc*80 + rem];
        }
        __syncthreads();
        #pragma unroll
        for (int dd=0; dd<16; ++dd){
            #pragma unroll
            for (int t=0; t<5; ++t){
                float wv[4], av[4];
                #pragma unroll
                for (int j=0;j<4;++j) wv[j] = Ws_[e0+j][dd*5+t];
                #pragma unroll
                for (int i=0;i<4;++i) av[i] = As_[l0+i+t][dc*16+dd];
                #pragma unroll
                for (int i=0;i<4;++i)
                    #pragma unroll
                    for (int j=0;j<4;++j)
                        acc[i][j] = fmaf(av[i], wv[j], acc[i][j]);
            }
        }
    }
    float gamma = *gamma_p;
    #pragma unroll
    for (int i=0;i<4;++i){
        int l = lc*64 + l0 + i;
        #pragma unroll
        for (int j=0;j<4;++j){
            int ee = e0 + j;
            float v = As_[l0+i+2][ee] + gamma*(acc[i][j] + conv_b[h*D_+ee]);
            out[((size_t)b*L_+l)*E_ + h*D_ + ee] = v;
        }
    }
}

extern "C" void kernel_launch(void* const* d_in, const int* in_sizes, int n_in,
                              void* d_out, int out_size, void* d_ws, size_t ws_size,
                              hipStream_t stream)
{
    const float* x     = (const float*)d_in[0];
    const float* Wq    = (const float*)d_in[1];
    const float* bq    = (const float*)d_in[2];
    const float* lnq_g = (const float*)d_in[3];
    const float* lnq_b = (const float*)d_in[4];
    const float* Wk    = (const float*)d_in[5];
    const float* bk    = (const float*)d_in[6];
    const float* lnk_g = (const float*)d_in[7];
    const float* lnk_b = (const float*)d_in[8];
    const float* Wv    = (const float*)d_in[9];
    const float* bv    = (const float*)d_in[10];
    const float* lnv_g = (const float*)d_in[11];
    const float* lnv_b = (const float*)d_in[12];
    const float* Wphi_q= (const float*)d_in[13];
    const float* bphi_q= (const float*)d_in[14];
    const float* Wphi_k= (const float*)d_in[15];
    const float* bphi_k= (const float*)d_in[16];
    const float* lna_g = (const float*)d_in[17];
    const float* lna_b = (const float*)d_in[18];
    const float* W1    = (const float*)d_in[19];
    const float* b1    = (const float*)d_in[20];
    const float* W2    = (const float*)d_in[21];
    const float* b2    = (const float*)d_in[22];
    const float* gamma = (const float*)d_in[23];
    const float* conv_w= (const float*)d_in[24];
    const float* conv_b= (const float*)d_in[25];
    float* out = (float*)d_out;

    const size_t Msz = (size_t)M_ * E_;            // 64 MiB per buffer
    float* ws   = (float*)d_ws;
    float* buf0 = ws;                              // Q -> attn_ln
    float* buf1 = ws + 1*Msz;                      // K -> attn -> MLP hidden
    float* buf2 = ws + 2*Msz;                      // V -> attn+conv
    float* qg    = ws + 3*Msz;                     // B*E
    float* alpha = qg + B_*E_;                     // B*H*(L+1)
    float* KV    = alpha + (size_t)B_*H_*LK_;      // B*H*D*D
    float* Ksum  = KV + (size_t)B_*H_*D_*D_;       // B*H*D

    const size_t need = (3*Msz + (size_t)B_*E_ + (size_t)B_*H_*LK_
                         + (size_t)B_*H_*D_*D_ + (size_t)B_*H_*D_) * sizeof(float);
    if (ws_size < need) return;   // fail visibly (poisoned d_out), don't fault

    dim3 blk256(256);
    dim3 g1(E_/64, M_/64);
    // Q/K/V projections + LN
    hipLaunchKernelGGL((gemm_f32<0>), g1, blk256, 0, stream, x, Wq, bq, buf0, M_, E_, E_, nullptr, nullptr);
    hipLaunchKernelGGL((gemm_f32<0>), g1, blk256, 0, stream, x, Wk, bk, buf1, M_, E_, E_, nullptr, nullptr);
    hipLaunchKernelGGL((gemm_f32<0>), g1, blk256, 0, stream, x, Wv, bv, buf2, M_, E_, E_, nullptr, nullptr);
    layernorm_rows<<<M_, 256, 0, stream>>>(buf0, lnq_g, lnq_b, buf0);
    layernorm_rows<<<M_, 256, 0, stream>>>(buf1, lnk_g, lnk_b, buf1);
    layernorm_rows<<<M_, 256, 0, stream>>>(buf2, lnv_g, lnv_b, buf2);
    // global query mean
    hipMemsetAsync(qg, 0, B_*E_*sizeof(float), stream);
    qg_partial<<<B_*64, 1024, 0, stream>>>(buf0, qg);
    // alpha (softmax over Lk incl. zero token)
    rala_alpha<<<B_*H_, 256, 0, stream>>>(buf1, qg, alpha);
    // fused phiK -> KV, Ksum
    hipMemsetAsync(KV,   0, (size_t)B_*H_*D_*D_*sizeof(float), stream);
    hipMemsetAsync(Ksum, 0, (size_t)B_*H_*D_*sizeof(float), stream);
    phik_kv<<<(M_/256)*H_, 256, 0, stream>>>(buf1, buf2, Wphi_k, bphi_k, alpha, KV, Ksum);
    ksum_zero<<<B_*H_, 64, 0, stream>>>(bphi_k, alpha, Ksum);
    // fused phiQ -> attn (overwrites K in buf1)
    phiq_attn<<<(M_/64)*H_, 256, 0, stream>>>(buf0, Wphi_q, bphi_q, KV, Ksum, buf1);
    // local conv + residual -> buf2
    conv_residual<<<B_*H_*64, 256, 0, stream>>>(buf1, conv_w, conv_b, gamma, buf2);
    // final attention LN -> buf0
    layernorm_rows<<<M_, 256, 0, stream>>>(buf2, lna_g, lna_b, buf0);
    // MLP + residuals, 4 chunks of 4096 rows (out = attn_ln + mlp + x); hidden in buf1
    for (int c=0; c<4; ++c){
        const float* Ain = buf0 + (size_t)c*4096*E_;
        const float* xin = x    + (size_t)c*4096*E_;
        float* outc = out + (size_t)c*4096*E_;
        dim3 gA(MLP_/64, 4096/64);
        hipLaunchKernelGGL((gemm_f32<2>), gA, blk256, 0, stream, Ain, W1, b1, buf1, 4096, MLP_, E_, nullptr, nullptr);
        dim3 gB(E_/64, 4096/64);
        hipLaunchKernelGGL((gemm_f32<3>), gB, blk256, 0, stream, buf1, W2, b2, outc, 4096, E_, MLP_, Ain, xin);
    }
}

// Round 9
// 2028.748 us; speedup vs baseline: 3.8452x; 3.8452x over previous
//
#include <hip/hip_runtime.h>
#include <hip/hip_bf16.h>

#define B_ 4
#define L_ 4096
#define E_ 1024
#define H_ 16
#define D_ 64
#define MLP_ 4096
#define M_ (B_*L_)
#define LK_ (L_+1)

typedef short bf16x8 __attribute__((ext_vector_type(8)));
typedef float f32x4 __attribute__((ext_vector_type(4)));
typedef unsigned short u16;

__device__ __forceinline__ u16 f2bf(float f){
    union { float f; unsigned u; } x; x.f = f;
    unsigned r = x.u + 0x7FFFu + ((x.u >> 16) & 1u);
    return (u16)(r >> 16);
}
__device__ __forceinline__ float bf2f(u16 u){
    union { unsigned u; float f; } x; x.u = ((unsigned)u) << 16;
    return x.f;
}

// ---------------- weight convert+transpose: in f32 [K,N] -> out bf16 [N,K] ----------------
__global__ __launch_bounds__(256)
void wcvt(const float* __restrict__ in, u16* __restrict__ out, int K, int N)
{
    __shared__ float t[32][33];
    int tid = threadIdx.x;
    int tx = tid & 31, ty = tid >> 5;      // 8 rows per iter
    int bk = blockIdx.y, bn = blockIdx.x;
    #pragma unroll
    for (int i=0;i<4;++i)
        t[ty+8*i][tx] = in[(size_t)(bk*32 + ty + 8*i)*N + bn*32 + tx];
    __syncthreads();
    #pragma unroll
    for (int i=0;i<4;++i)
        out[(size_t)(bn*32 + ty + 8*i)*K + bk*32 + tx] = f2bf(t[tx][ty+8*i]);
}

// ---------------- x convert f32 -> bf16 ----------------
__global__ __launch_bounds__(256)
void xcvt(const float* __restrict__ in, u16* __restrict__ out)
{
    size_t i = ((size_t)blockIdx.x*256 + threadIdx.x)*4;
    float4 v = *(const float4*)(in + i);
    ushort4 o; o.x=f2bf(v.x); o.y=f2bf(v.y); o.z=f2bf(v.z); o.w=f2bf(v.w);
    *(ushort4*)(out + i) = o;
}

// ---------------- bf16 MFMA GEMM: C = A[M,K] @ Wt[N,K]^T + bias ----------------
// EPI 0: bf16 out; 1: tanh+1 -> bf16; 2: (tanh+1)*alpha -> bf16 (P1=alpha, N=1024);
// EPI 3: gelu -> bf16; 4: f32 out = v + P1 + P2
template<int EPI>
__global__ __launch_bounds__(256)
void gemm_bf16(const u16* __restrict__ A, const u16* __restrict__ Wt,
               const float* __restrict__ bias, void* __restrict__ Cout,
               int M, int N, int K,
               const float* __restrict__ P1, const float* __restrict__ P2)
{
    __shared__ u16 As[128*64];
    __shared__ u16 Bs[128*64];
    const int tid = threadIdx.x;
    const int bm = blockIdx.y, bn = blockIdx.x;
    const int lane = tid & 63, w = tid >> 6;
    const int wr = w >> 1, wc = w & 1;
    const int row16 = lane & 15, kb = lane >> 4;
    f32x4 acc[4][4] = {};

    for (int kt = 0; kt < K; kt += 64) {
        #pragma unroll
        for (int i = 0; i < 4; ++i) {
            int c = tid + 256*i;               // 0..1023
            int row = c >> 3, kc = c & 7;
            uint4 va = *(const uint4*)(A  + (size_t)(bm*128 + row)*K + kt + kc*8);
            uint4 vb = *(const uint4*)(Wt + (size_t)(bn*128 + row)*K + kt + kc*8);
            int off = row*128 + ((kc*16) ^ ((row & 7) << 4));
            *(uint4*)((char*)As + off) = va;
            *(uint4*)((char*)Bs + off) = vb;
        }
        __syncthreads();
        #pragma unroll
        for (int kk = 0; kk < 2; ++kk) {
            bf16x8 af[4], bfr[4];
            #pragma unroll
            for (int mi = 0; mi < 4; ++mi) {
                int r = wr*64 + mi*16 + row16;
                int off = r*128 + ((kk*64 + kb*16) ^ ((row16 & 7) << 4));
                af[mi] = *(const bf16x8*)((const char*)As + off);
            }
            #pragma unroll
            for (int nj = 0; nj < 4; ++nj) {
                int r = wc*64 + nj*16 + row16;
                int off = r*128 + ((kk*64 + kb*16) ^ ((row16 & 7) << 4));
                bfr[nj] = *(const bf16x8*)((const char*)Bs + off);
            }
            #pragma unroll
            for (int mi = 0; mi < 4; ++mi)
                #pragma unroll
                for (int nj = 0; nj < 4; ++nj)
                    acc[mi][nj] = __builtin_amdgcn_mfma_f32_16x16x32_bf16(af[mi], bfr[nj], acc[mi][nj], 0, 0, 0);
        }
        __syncthreads();
    }
    #pragma unroll
    for (int nj = 0; nj < 4; ++nj) {
        int col = bn*128 + wc*64 + nj*16 + row16;
        float bcol = bias[col];
        #pragma unroll
        for (int mi = 0; mi < 4; ++mi) {
            int rbase = bm*128 + wr*64 + mi*16 + kb*4;
            #pragma unroll
            for (int r = 0; r < 4; ++r) {
                int row = rbase + r;
                float v = acc[mi][nj][r] + bcol;
                if (EPI == 1) v = tanhf(v) + 1.0f;
                if (EPI == 2) {
                    int b = row >> 12, l = row & 4095, h = col >> 6;
                    v = (tanhf(v) + 1.0f) * P1[(size_t)(b*16 + h)*LK_ + 1 + l];
                }
                if (EPI == 3) v = 0.5f*v*(1.0f + erff(v*0.70710678118654752f));
                if (EPI == 4) {
                    ((float*)Cout)[(size_t)row*N + col] = v + P1[(size_t)row*N + col] + P2[(size_t)row*N + col];
                } else {
                    ((u16*)Cout)[(size_t)row*N + col] = f2bf(v);
                }
            }
        }
    }
}

// ---------------- row LayerNorm over E=1024 (bf16 in-place) ----------------
__global__ __launch_bounds__(256)
void ln_bf16(u16* __restrict__ x, const float* __restrict__ g, const float* __restrict__ bta)
{
    __shared__ float red[8];
    const int row = blockIdx.x, tid = threadIdx.x;
    u16* p = x + (size_t)row*E_;
    ushort4 raw = *(const ushort4*)(p + tid*4);
    float v[4] = {bf2f(raw.x), bf2f(raw.y), bf2f(raw.z), bf2f(raw.w)};
    float s=0.f, s2=0.f;
    #pragma unroll
    for (int i=0;i<4;++i){ s += v[i]; s2 += v[i]*v[i]; }
    #pragma unroll
    for (int o=32;o;o>>=1){ s += __shfl_xor(s,o); s2 += __shfl_xor(s2,o); }
    int wv = tid >> 6;
    if ((tid & 63) == 0){ red[wv] = s; red[4+wv] = s2; }
    __syncthreads();
    s  = red[0]+red[1]+red[2]+red[3];
    s2 = red[4]+red[5]+red[6]+red[7];
    float mu = s * (1.0f/E_);
    float var = s2 * (1.0f/E_) - mu*mu;
    float rs = rsqrtf(var + 1e-5f);
    ushort4 o4;
    float r0 = (v[0]-mu)*rs*g[tid*4+0] + bta[tid*4+0];
    float r1 = (v[1]-mu)*rs*g[tid*4+1] + bta[tid*4+1];
    float r2 = (v[2]-mu)*rs*g[tid*4+2] + bta[tid*4+2];
    float r3 = (v[3]-mu)*rs*g[tid*4+3] + bta[tid*4+3];
    o4.x=f2bf(r0); o4.y=f2bf(r1); o4.z=f2bf(r2); o4.w=f2bf(r3);
    *(ushort4*)(p + tid*4) = o4;
}

// ---------------- final LN: bf16 in -> f32 out + bf16 out ----------------
__global__ __launch_bounds__(256)
void ln_dual(const u16* __restrict__ x, const float* __restrict__ g, const float* __restrict__ bta,
             float* __restrict__ of, u16* __restrict__ ob)
{
    __shared__ float red[8];
    const int row = blockIdx.x, tid = threadIdx.x;
    const u16* p = x + (size_t)row*E_;
    ushort4 raw = *(const ushort4*)(p + tid*4);
    float v[4] = {bf2f(raw.x), bf2f(raw.y), bf2f(raw.z), bf2f(raw.w)};
    float s=0.f, s2=0.f;
    #pragma unroll
    for (int i=0;i<4;++i){ s += v[i]; s2 += v[i]*v[i]; }
    #pragma unroll
    for (int o=32;o;o>>=1){ s += __shfl_xor(s,o); s2 += __shfl_xor(s2,o); }
    int wv = tid >> 6;
    if ((tid & 63) == 0){ red[wv] = s; red[4+wv] = s2; }
    __syncthreads();
    s  = red[0]+red[1]+red[2]+red[3];
    s2 = red[4]+red[5]+red[6]+red[7];
    float mu = s * (1.0f/E_);
    float var = s2 * (1.0f/E_) - mu*mu;
    float rs = rsqrtf(var + 1e-5f);
    float4 rf; ushort4 o4;
    rf.x = (v[0]-mu)*rs*g[tid*4+0] + bta[tid*4+0];
    rf.y = (v[1]-mu)*rs*g[tid*4+1] + bta[tid*4+1];
    rf.z = (v[2]-mu)*rs*g[tid*4+2] + bta[tid*4+2];
    rf.w = (v[3]-mu)*rs*g[tid*4+3] + bta[tid*4+3];
    o4.x=f2bf(rf.x); o4.y=f2bf(rf.y); o4.z=f2bf(rf.z); o4.w=f2bf(rf.w);
    *(float4*)(of + (size_t)row*E_ + tid*4) = rf;
    *(ushort4*)(ob + (size_t)row*E_ + tid*4) = o4;
}

// ---------------- qg partial sums (bf16 Q) ----------------
__global__ __launch_bounds__(1024)
void qg_partial(const u16* __restrict__ Q, float* __restrict__ qg)
{
    int b = blockIdx.x >> 6;
    int c = blockIdx.x & 63;
    int e = threadIdx.x;
    float s = 0.f;
    const u16* p = Q + ((size_t)b*L_ + c*64)*E_ + e;
    for (int l=0; l<64; ++l) s += bf2f(p[(size_t)l*E_]);
    atomicAdd(&qg[b*E_ + e], s);
}

// ---------------- scores -> softmax -> alpha (zero token at index 0) ----------------
__global__ __launch_bounds__(256)
void rala_alpha(const u16* __restrict__ K, const float* __restrict__ qg,
                float* __restrict__ alpha)
{
    __shared__ float sc[L_];
    __shared__ float qs[D_];
    __shared__ float red[8];
    int bh = blockIdx.x; int b = bh >> 4, h = bh & 15;
    int tid = threadIdx.x;
    if (tid < D_) qs[tid] = qg[b*E_ + h*D_ + tid] * (1.0f/(L_ * 8.0f));
    __syncthreads();
    int wv = tid >> 6, lane = tid & 63;
    const u16* Kb = K + (size_t)b*L_*E_ + h*D_ + lane;
    for (int l = wv; l < L_; l += 4) {
        float v = bf2f(Kb[(size_t)l*E_]) * qs[lane];
        #pragma unroll
        for (int o=32;o;o>>=1) v += __shfl_xor(v,o);
        if (lane==0) sc[l] = v;
    }
    __syncthreads();
    float mx = 0.f;
    for (int i=tid;i<L_;i+=256) mx = fmaxf(mx, sc[i]);
    #pragma unroll
    for (int o=32;o;o>>=1) mx = fmaxf(mx, __shfl_xor(mx,o));
    if (lane==0) red[wv] = mx;
    __syncthreads();
    mx = fmaxf(fmaxf(red[0],red[1]), fmaxf(red[2],red[3]));
    float sum = 0.f;
    for (int i=tid;i<L_;i+=256){ float e = expf(sc[i]-mx); sc[i]=e; sum += e; }
    #pragma unroll
    for (int o=32;o;o>>=1) sum += __shfl_xor(sum,o);
    __syncthreads();
    if (lane==0) red[4+wv] = sum;
    __syncthreads();
    float Z = red[4]+red[5]+red[6]+red[7] + expf(-mx);
    float scale = (float)L_ / Z;
    float* al = alpha + (size_t)bh*LK_;
    for (int i=tid;i<L_;i+=256) al[1+i] = sc[i]*scale;
    if (tid==0) al[0] = expf(-mx)*scale;
}

// ---------------- KV[b,h,64,64] & Ksum[b,h,64] from scaled phiKs (bf16) & V (bf16) ----------------
#define NS_ 8
__global__ __launch_bounds__(256)
void kv_partial(const u16* __restrict__ phiKs, const u16* __restrict__ Vb,
                float* __restrict__ KV, float* __restrict__ Ksum)
{
    __shared__ float Ps[64][65];
    __shared__ float Vs[64][65];
    int blk = blockIdx.x;
    int s = blk & (NS_-1);
    int h = (blk >> 3) & 15;
    int b = blk >> 7;
    int tid = threadIdx.x;
    int tx = tid & 15, ty = tid >> 4;
    const size_t bh = (size_t)(b*H_ + h);
    float acc[4][4] = {};
    float ksl = 0.f;
    for (int ch = 0; ch < 8; ++ch) {
        int lbase = s*512 + ch*64;
        #pragma unroll
        for (int i=0;i<16;++i){
            int idx = tid + i*256;
            int r = idx >> 6, c2 = idx & 63;
            size_t g = ((size_t)b*L_ + lbase + r)*E_ + h*64 + c2;
            Ps[r][c2] = bf2f(phiKs[g]);
            Vs[r][c2] = bf2f(Vb[g]);
        }
        __syncthreads();
        #pragma unroll 8
        for (int l=0; l<64; ++l){
            float p[4], vv[4];
            #pragma unroll
            for (int i=0;i<4;++i) p[i] = Ps[l][ty*4+i];
            #pragma unroll
            for (int j=0;j<4;++j) vv[j] = Vs[l][tx*4+j];
            #pragma unroll
            for (int i=0;i<4;++i)
                #pragma unroll
                for (int j=0;j<4;++j)
                    acc[i][j] = fmaf(p[i], vv[j], acc[i][j]);
        }
        if (tid < 64){
            float t = 0.f;
            #pragma unroll 8
            for (int l=0; l<64; ++l) t += Ps[l][tid];
            ksl += t;
        }
        __syncthreads();
    }
    #pragma unroll
    for (int i=0;i<4;++i)
        #pragma unroll
        for (int j=0;j<4;++j)
            atomicAdd(&KV[(bh*D_ + ty*4+i)*D_ + tx*4+j], acc[i][j]);
    if (tid < 64) atomicAdd(&Ksum[bh*D_ + tid], ksl);
}

// zero-token: Ksum += (tanh(bphi_k)+1) * alpha0
__global__ void ksum_zero(const float* __restrict__ bphi_k,
                          const float* __restrict__ alpha, float* __restrict__ Ksum)
{
    int bh = blockIdx.x; int h = bh & 15; int d = threadIdx.x;
    float a0 = alpha[(size_t)bh*LK_];
    Ksum[(size_t)bh*D_ + d] += (tanhf(bphi_k[h*D_ + d]) + 1.0f) * a0;
}

// ---------------- attn = (phiQ @ KV) / (phiQ . Ksum + eps), bf16 out ----------------
__global__ __launch_bounds__(256)
void attn_core(const u16* __restrict__ phiQ, const float* __restrict__ KV,
               const float* __restrict__ Ksum, u16* __restrict__ attn)
{
    __shared__ float KVs[64][65];
    __shared__ float Ps[64][65];
    __shared__ float Ks_[64];
    int gid = blockIdx.x;
    int h = gid & 15; int rchunk = gid >> 4;
    int row0 = rchunk * 64;
    int b = row0 >> 12;
    const size_t bh = (size_t)(b*H_ + h);
    int tid = threadIdx.x;
    int tx = tid & 15, ty = tid >> 4;
    #pragma unroll
    for (int i=0;i<16;++i){
        int idx = tid + i*256;
        int r = idx >> 6, c2 = idx & 63;
        KVs[r][c2] = KV[bh*D_*D_ + r*64 + c2];
        Ps[r][c2]  = bf2f(phiQ[((size_t)row0 + r)*E_ + h*64 + c2]);
    }
    if (tid < 64) Ks_[tid] = Ksum[bh*D_ + tid];
    __syncthreads();
    float num[4][4] = {};
    float den[4] = {};
    for (int d=0; d<64; ++d){
        float kd = Ks_[d];
        float4 kv4 = *(const float4*)&KVs[d][tx*4];
        float kvv[4] = {kv4.x, kv4.y, kv4.z, kv4.w};
        #pragma unroll
        for (int i=0;i<4;++i){
            float q = Ps[ty*4+i][d];
            den[i] = fmaf(q, kd, den[i]);
            #pragma unroll
            for (int j=0;j<4;++j)
                num[i][j] = fmaf(q, kvv[j], num[i][j]);
        }
    }
    #pragma unroll
    for (int i=0;i<4;++i){
        float r = 1.0f / (den[i] + 1e-6f);
        #pragma unroll
        for (int j=0;j<4;++j)
            attn[((size_t)row0 + ty*4 + i)*E_ + h*64 + tx*4 + j] = f2bf(num[i][j] * r);
    }
}

// ---------------- grouped conv (k=5,pad=2,groups=H) + gated residual (bf16 io) ----------------
__global__ __launch_bounds__(256)
void conv_residual(const u16* __restrict__ attn, const float* __restrict__ conv_w,
                   const float* __restrict__ conv_b, const float* __restrict__ gamma_p,
                   u16* __restrict__ out)
{
    __shared__ float As_[68][65];
    __shared__ float Ws_[64][81];
    int blk = blockIdx.x;
    int lc = blk & 63; int h = (blk>>6) & 15; int b = blk >> 10;
    int tid = threadIdx.x;
    int tx = tid & 15, ty = tid >> 4;
    for (int i=tid; i<68*64; i+=256){
        int r = i>>6, cc = i&63;
        int l = lc*64 - 2 + r;
        As_[r][cc] = (l>=0 && l<L_) ? bf2f(attn[((size_t)b*L_+l)*E_ + h*D_ + cc]) : 0.f;
    }
    int e0 = tx*4, l0 = ty*4;
    float acc[4][4] = {};
    for (int dc=0; dc<4; ++dc){
        __syncthreads();
        for (int i=tid; i<64*80; i+=256){
            int ee = i/80, rem = i%80;
            Ws_[ee][rem] = conv_w[((size_t)(h*D_+ee))*320 + dc*80 + rem];
        }
        __syncthreads();
        #pragma unroll
        for (int dd=0; dd<16; ++dd){
            #pragma unroll
            for (int t=0; t<5; ++t){
                float wv[4], av[4];
                #pragma unroll
                for (int j=0;j<4;++j) wv[j] = Ws_[e0+j][dd*5+t];
                #pragma unroll
                for (int i=0;i<4;++i) av[i] = As_[l0+i+t][dc*16+dd];
                #pragma unroll
                for (int i=0;i<4;++i)
                    #pragma unroll
                    for (int j=0;j<4;++j)
                        acc[i][j] = fmaf(av[i], wv[j], acc[i][j]);
            }
        }
    }
    float gamma = *gamma_p;
    #pragma unroll
    for (int i=0;i<4;++i){
        int l = lc*64 + l0 + i;
        #pragma unroll
        for (int j=0;j<4;++j){
            int ee = e0 + j;
            float v = As_[l0+i+2][ee] + gamma*(acc[i][j] + conv_b[h*D_+ee]);
            out[((size_t)b*L_+l)*E_ + h*D_ + ee] = f2bf(v);
        }
    }
}

extern "C" void kernel_launch(void* const* d_in, const int* in_sizes, int n_in,
                              void* d_out, int out_size, void* d_ws, size_t ws_size,
                              hipStream_t stream)
{
    const float* x     = (const float*)d_in[0];
    const float* Wq    = (const float*)d_in[1];
    const float* bq    = (const float*)d_in[2];
    const float* lnq_g = (const float*)d_in[3];
    const float* lnq_b = (const float*)d_in[4];
    const float* Wk    = (const float*)d_in[5];
    const float* bk    = (const float*)d_in[6];
    const float* lnk_g = (const float*)d_in[7];
    const float* lnk_b = (const float*)d_in[8];
    const float* Wv    = (const float*)d_in[9];
    const float* bv    = (const float*)d_in[10];
    const float* lnv_g = (const float*)d_in[11];
    const float* lnv_b = (const float*)d_in[12];
    const float* Wphi_q= (const float*)d_in[13];
    const float* bphi_q= (const float*)d_in[14];
    const float* Wphi_k= (const float*)d_in[15];
    const float* bphi_k= (const float*)d_in[16];
    const float* lna_g = (const float*)d_in[17];
    const float* lna_b = (const float*)d_in[18];
    const float* W1    = (const float*)d_in[19];
    const float* b1    = (const float*)d_in[20];
    const float* W2    = (const float*)d_in[21];
    const float* b2    = (const float*)d_in[22];
    const float* gamma = (const float*)d_in[23];
    const float* conv_w= (const float*)d_in[24];
    const float* conv_b= (const float*)d_in[25];
    float* out = (float*)d_out;

    // ---- workspace layout (bytes) ----
    char* base = (char*)d_ws;
    const size_t WT_SQ = (size_t)E_*E_*2;            // 2 MiB each
    const size_t WT_ALL = 5*WT_SQ + 2*(size_t)E_*MLP_*2;
    const size_t BUF = (size_t)M_*E_*2;              // 32 MiB bf16 buffer
    u16* Wqt  = (u16*)base;
    u16* Wkt  = (u16*)(base + 1*WT_SQ);
    u16* Wvt  = (u16*)(base + 2*WT_SQ);
    u16* Wqpt = (u16*)(base + 3*WT_SQ);
    u16* Wkpt = (u16*)(base + 4*WT_SQ);
    u16* W1t  = (u16*)(base + 5*WT_SQ);                       // [4096,1024]
    u16* W2t  = (u16*)(base + 5*WT_SQ + (size_t)E_*MLP_*2);   // [1024,4096]
    char* bufs = base + WT_ALL;
    u16* xb = (u16*)(bufs);            // x bf16 / phiKs / aln_b
    u16* Qb = (u16*)(bufs + 1*BUF);    // Q / attn2_b / h1
    u16* Kb = (u16*)(bufs + 2*BUF);    // K / attn_b / aln_f(lo half)
    u16* Vb = (u16*)(bufs + 3*BUF);    // V / phiQ / aln_f(hi half)
    char* small = bufs + 4*BUF;
    float* qg    = (float*)small;                       // B*E
    float* alpha = qg + B_*E_;                          // B*H*LK
    float* KV    = alpha + (size_t)B_*H_*LK_;           // B*H*D*D
    float* Ksum  = KV + (size_t)B_*H_*D_*D_;            // B*H*D
    const size_t need = WT_ALL + 4*BUF +
        ((size_t)B_*E_ + (size_t)B_*H_*LK_ + (size_t)B_*H_*D_*D_ + (size_t)B_*H_*D_)*4;
    if (ws_size < need) return;    // fail visibly rather than fault

    u16* phiKs = xb;                 // after QKV GEMMs, xb is dead
    u16* phiQ  = Vb;                 // after kv_partial, Vb is dead
    u16* attn_b  = Kb;               // after rala+phiK gemm, Kb dead
    u16* attn2_b = Qb;               // after phiQ gemm, Qb dead
    float* aln_f = (float*)Kb;       // 64 MiB spanning Kb+Vb
    u16* aln_b   = xb;
    u16* h1      = Qb;

    dim3 blk256(256);
    // weight conversions (transpose to [N,K] bf16)
    wcvt<<<dim3(32,32),  blk256, 0, stream>>>(Wq, Wqt, E_, E_);
    wcvt<<<dim3(32,32),  blk256, 0, stream>>>(Wk, Wkt, E_, E_);
    wcvt<<<dim3(32,32),  blk256, 0, stream>>>(Wv, Wvt, E_, E_);
    wcvt<<<dim3(32,32),  blk256, 0, stream>>>(Wphi_q, Wqpt, E_, E_);
    wcvt<<<dim3(32,32),  blk256, 0, stream>>>(Wphi_k, Wkpt, E_, E_);
    wcvt<<<dim3(128,32), blk256, 0, stream>>>(W1, W1t, E_, MLP_);
    wcvt<<<dim3(32,128), blk256, 0, stream>>>(W2, W2t, MLP_, E_);
    xcvt<<<M_*E_/1024, blk256, 0, stream>>>(x, xb);
    // QKV projections (bf16 out) + LN in place
    hipLaunchKernelGGL((gemm_bf16<0>), dim3(8,128), blk256, 0, stream, xb, Wqt, bq, Qb, M_, E_, E_, nullptr, nullptr);
    hipLaunchKernelGGL((gemm_bf16<0>), dim3(8,128), blk256, 0, stream, xb, Wkt, bk, Kb, M_, E_, E_, nullptr, nullptr);
    hipLaunchKernelGGL((gemm_bf16<0>), dim3(8,128), blk256, 0, stream, xb, Wvt, bv, Vb, M_, E_, E_, nullptr, nullptr);
    ln_bf16<<<M_, 256, 0, stream>>>(Qb, lnq_g, lnq_b);
    ln_bf16<<<M_, 256, 0, stream>>>(Kb, lnk_g, lnk_b);
    ln_bf16<<<M_, 256, 0, stream>>>(Vb, lnv_g, lnv_b);
    // qg and alpha
    hipMemsetAsync(qg, 0, B_*E_*sizeof(float), stream);
    qg_partial<<<B_*64, 1024, 0, stream>>>(Qb, qg);
    rala_alpha<<<B_*H_, 256, 0, stream>>>(Kb, qg, alpha);
    // phiK (alpha folded) -> phiKs (= xb region)
    hipLaunchKernelGGL((gemm_bf16<2>), dim3(8,128), blk256, 0, stream, Kb, Wkpt, bphi_k, phiKs, M_, E_, E_, alpha, nullptr);
    // KV / Ksum
    hipMemsetAsync(KV,   0, (size_t)B_*H_*D_*D_*sizeof(float), stream);
    hipMemsetAsync(Ksum, 0, (size_t)B_*H_*D_*sizeof(float), stream);
    kv_partial<<<B_*H_*NS_, 256, 0, stream>>>(phiKs, Vb, KV, Ksum);
    ksum_zero<<<B_*H_, 64, 0, stream>>>(bphi_k, alpha, Ksum);
    // phiQ (= Vb region, V dead after kv_partial)
    hipLaunchKernelGGL((gemm_bf16<1>), dim3(8,128), blk256, 0, stream, Qb, Wqpt, bphi_q, phiQ, M_, E_, E_, nullptr, nullptr);
    // attention output -> attn_b (= Kb region)
    attn_core<<<(M_/64)*H_, 256, 0, stream>>>(phiQ, KV, Ksum, attn_b);
    // conv + gated residual -> attn2_b (= Qb region)
    conv_residual<<<B_*H_*64, 256, 0, stream>>>(attn_b, conv_w, conv_b, gamma, attn2_b);
    // final LN: f32 copy (Kb+Vb) + bf16 copy (xb)
    ln_dual<<<M_, 256, 0, stream>>>(attn2_b, lna_g, lna_b, aln_f, aln_b);
    // MLP + residuals, 4 chunks of 4096 rows; hidden h1 in Qb region
    for (int c=0; c<4; ++c){
        const u16* Ain   = aln_b + (size_t)c*4096*E_;
        const float* Rf  = aln_f + (size_t)c*4096*E_;
        const float* xin = x     + (size_t)c*4096*E_;
        float* outc = out + (size_t)c*4096*E_;
        hipLaunchKernelGGL((gemm_bf16<3>), dim3(32,32), blk256, 0, stream, Ain, W1t, b1, h1, 4096, MLP_, E_, nullptr, nullptr);
        hipLaunchKernelGGL((gemm_bf16<4>), dim3(8,32),  blk256, 0, stream, h1, W2t, b2, outc, 4096, E_, MLP_, Rf, xin);
    }
}

// Round 10
// 1585.277 us; speedup vs baseline: 4.9208x; 1.2797x over previous
//
#include <hip/hip_runtime.h>
#include <hip/hip_bf16.h>

#define B_ 4
#define L_ 4096
#define E_ 1024
#define H_ 16
#define D_ 64
#define MLP_ 4096
#define M_ (B_*L_)
#define LK_ (L_+1)

typedef short bf16x8 __attribute__((ext_vector_type(8)));
typedef float f32x4 __attribute__((ext_vector_type(4)));
typedef unsigned short u16;

__device__ __forceinline__ u16 f2bf(float f){
    union { float f; unsigned u; } x; x.f = f;
    unsigned r = x.u + 0x7FFFu + ((x.u >> 16) & 1u);
    return (u16)(r >> 16);
}
__device__ __forceinline__ float bf2f(u16 u){
    union { unsigned u; float f; } x; x.u = ((unsigned)u) << 16;
    return x.f;
}

// ---------------- weight convert+transpose: in f32 [K,N] -> out bf16 [N,K] ----------------
__global__ __launch_bounds__(256)
void wcvt(const float* __restrict__ in, u16* __restrict__ out, int K, int N)
{
    __shared__ float t[32][33];
    int tid = threadIdx.x;
    int tx = tid & 31, ty = tid >> 5;      // 8 rows per iter
    int bk = blockIdx.y, bn = blockIdx.x;
    #pragma unroll
    for (int i=0;i<4;++i)
        t[ty+8*i][tx] = in[(size_t)(bk*32 + ty + 8*i)*N + bn*32 + tx];
    __syncthreads();
    #pragma unroll
    for (int i=0;i<4;++i)
        out[(size_t)(bn*32 + ty + 8*i)*K + bk*32 + tx] = f2bf(t[tx][ty+8*i]);
}

// ---------------- x convert f32 -> bf16 ----------------
__global__ __launch_bounds__(256)
void xcvt(const float* __restrict__ in, u16* __restrict__ out)
{
    size_t i = ((size_t)blockIdx.x*256 + threadIdx.x)*4;
    float4 v = *(const float4*)(in + i);
    ushort4 o; o.x=f2bf(v.x); o.y=f2bf(v.y); o.z=f2bf(v.z); o.w=f2bf(v.w);
    *(ushort4*)(out + i) = o;
}

// ---------------- bf16 MFMA GEMM: C = A[M,K] @ Wt[N,K]^T + bias ----------------
// EPI 0: bf16 out; 1: tanh+1 -> bf16; 2: (tanh+1)*alpha -> bf16 (P1=alpha, N=1024);
// EPI 3: gelu -> bf16; 4: f32 out = v + P1 + P2
template<int EPI>
__global__ __launch_bounds__(256)
void gemm_bf16(const u16* __restrict__ A, const u16* __restrict__ Wt,
               const float* __restrict__ bias, void* __restrict__ Cout,
               int M, int N, int K,
               const float* __restrict__ P1, const float* __restrict__ P2)
{
    __shared__ u16 As[128*64];
    __shared__ u16 Bs[128*64];
    const int tid = threadIdx.x;
    const int bm = blockIdx.y, bn = blockIdx.x;
    const int lane = tid & 63, w = tid >> 6;
    const int wr = w >> 1, wc = w & 1;
    const int row16 = lane & 15, kb = lane >> 4;
    f32x4 acc[4][4] = {};

    for (int kt = 0; kt < K; kt += 64) {
        #pragma unroll
        for (int i = 0; i < 4; ++i) {
            int c = tid + 256*i;               // 0..1023
            int row = c >> 3, kc = c & 7;
            uint4 va = *(const uint4*)(A  + (size_t)(bm*128 + row)*K + kt + kc*8);
            uint4 vb = *(const uint4*)(Wt + (size_t)(bn*128 + row)*K + kt + kc*8);
            int off = row*128 + ((kc*16) ^ ((row & 7) << 4));
            *(uint4*)((char*)As + off) = va;
            *(uint4*)((char*)Bs + off) = vb;
        }
        __syncthreads();
        #pragma unroll
        for (int kk = 0; kk < 2; ++kk) {
            bf16x8 af[4], bfr[4];
            #pragma unroll
            for (int mi = 0; mi < 4; ++mi) {
                int r = wr*64 + mi*16 + row16;
                int off = r*128 + ((kk*64 + kb*16) ^ ((row16 & 7) << 4));
                af[mi] = *(const bf16x8*)((const char*)As + off);
            }
            #pragma unroll
            for (int nj = 0; nj < 4; ++nj) {
                int r = wc*64 + nj*16 + row16;
                int off = r*128 + ((kk*64 + kb*16) ^ ((row16 & 7) << 4));
                bfr[nj] = *(const bf16x8*)((const char*)Bs + off);
            }
            #pragma unroll
            for (int mi = 0; mi < 4; ++mi)
                #pragma unroll
                for (int nj = 0; nj < 4; ++nj)
                    acc[mi][nj] = __builtin_amdgcn_mfma_f32_16x16x32_bf16(af[mi], bfr[nj], acc[mi][nj], 0, 0, 0);
        }
        __syncthreads();
    }
    #pragma unroll
    for (int nj = 0; nj < 4; ++nj) {
        int col = bn*128 + wc*64 + nj*16 + row16;
        float bcol = bias[col];
        #pragma unroll
        for (int mi = 0; mi < 4; ++mi) {
            int rbase = bm*128 + wr*64 + mi*16 + kb*4;
            #pragma unroll
            for (int r = 0; r < 4; ++r) {
                int row = rbase + r;
                float v = acc[mi][nj][r] + bcol;
                if (EPI == 1) v = tanhf(v) + 1.0f;
                if (EPI == 2) {
                    int b = row >> 12, l = row & 4095, h = col >> 6;
                    v = (tanhf(v) + 1.0f) * P1[(size_t)(b*16 + h)*LK_ + 1 + l];
                }
                if (EPI == 3) v = 0.5f*v*(1.0f + erff(v*0.70710678118654752f));
                if (EPI == 4) {
                    ((float*)Cout)[(size_t)row*N + col] = v + P1[(size_t)row*N + col] + P2[(size_t)row*N + col];
                } else {
                    ((u16*)Cout)[(size_t)row*N + col] = f2bf(v);
                }
            }
        }
    }
}

// ---------------- row LayerNorm over E=1024 (bf16 in-place) ----------------
__global__ __launch_bounds__(256)
void ln_bf16(u16* __restrict__ x, const float* __restrict__ g, const float* __restrict__ bta)
{
    __shared__ float red[8];
    const int row = blockIdx.x, tid = threadIdx.x;
    u16* p = x + (size_t)row*E_;
    ushort4 raw = *(const ushort4*)(p + tid*4);
    float v[4] = {bf2f(raw.x), bf2f(raw.y), bf2f(raw.z), bf2f(raw.w)};
    float s=0.f, s2=0.f;
    #pragma unroll
    for (int i=0;i<4;++i){ s += v[i]; s2 += v[i]*v[i]; }
    #pragma unroll
    for (int o=32;o;o>>=1){ s += __shfl_xor(s,o); s2 += __shfl_xor(s2,o); }
    int wv = tid >> 6;
    if ((tid & 63) == 0){ red[wv] = s; red[4+wv] = s2; }
    __syncthreads();
    s  = red[0]+red[1]+red[2]+red[3];
    s2 = red[4]+red[5]+red[6]+red[7];
    float mu = s * (1.0f/E_);
    float var = s2 * (1.0f/E_) - mu*mu;
    float rs = rsqrtf(var + 1e-5f);
    ushort4 o4;
    float r0 = (v[0]-mu)*rs*g[tid*4+0] + bta[tid*4+0];
    float r1 = (v[1]-mu)*rs*g[tid*4+1] + bta[tid*4+1];
    float r2 = (v[2]-mu)*rs*g[tid*4+2] + bta[tid*4+2];
    float r3 = (v[3]-mu)*rs*g[tid*4+3] + bta[tid*4+3];
    o4.x=f2bf(r0); o4.y=f2bf(r1); o4.z=f2bf(r2); o4.w=f2bf(r3);
    *(ushort4*)(p + tid*4) = o4;
}

// ---------------- final LN: bf16 in -> f32 out + bf16 out ----------------
__global__ __launch_bounds__(256)
void ln_dual(const u16* __restrict__ x, const float* __restrict__ g, const float* __restrict__ bta,
             float* __restrict__ of, u16* __restrict__ ob)
{
    __shared__ float red[8];
    const int row = blockIdx.x, tid = threadIdx.x;
    const u16* p = x + (size_t)row*E_;
    ushort4 raw = *(const ushort4*)(p + tid*4);
    float v[4] = {bf2f(raw.x), bf2f(raw.y), bf2f(raw.z), bf2f(raw.w)};
    float s=0.f, s2=0.f;
    #pragma unroll
    for (int i=0;i<4;++i){ s += v[i]; s2 += v[i]*v[i]; }
    #pragma unroll
    for (int o=32;o;o>>=1){ s += __shfl_xor(s,o); s2 += __shfl_xor(s2,o); }
    int wv = tid >> 6;
    if ((tid & 63) == 0){ red[wv] = s; red[4+wv] = s2; }
    __syncthreads();
    s  = red[0]+red[1]+red[2]+red[3];
    s2 = red[4]+red[5]+red[6]+red[7];
    float mu = s * (1.0f/E_);
    float var = s2 * (1.0f/E_) - mu*mu;
    float rs = rsqrtf(var + 1e-5f);
    float4 rf; ushort4 o4;
    rf.x = (v[0]-mu)*rs*g[tid*4+0] + bta[tid*4+0];
    rf.y = (v[1]-mu)*rs*g[tid*4+1] + bta[tid*4+1];
    rf.z = (v[2]-mu)*rs*g[tid*4+2] + bta[tid*4+2];
    rf.w = (v[3]-mu)*rs*g[tid*4+3] + bta[tid*4+3];
    o4.x=f2bf(rf.x); o4.y=f2bf(rf.y); o4.z=f2bf(rf.z); o4.w=f2bf(rf.w);
    *(float4*)(of + (size_t)row*E_ + tid*4) = rf;
    *(ushort4*)(ob + (size_t)row*E_ + tid*4) = o4;
}

// ---------------- qg partial sums (bf16 Q) ----------------
__global__ __launch_bounds__(1024)
void qg_partial(const u16* __restrict__ Q, float* __restrict__ qg)
{
    int b = blockIdx.x >> 6;
    int c = blockIdx.x & 63;
    int e = threadIdx.x;
    float s = 0.f;
    const u16* p = Q + ((size_t)b*L_ + c*64)*E_ + e;
    for (int l=0; l<64; ++l) s += bf2f(p[(size_t)l*E_]);
    atomicAdd(&qg[b*E_ + e], s);
}

// ---------------- RALA scores: scores[b,h,l] = dot(qs[b,h,:], K[b,l,h,:]) ----------------
// block = 64 consecutive rows; wave reads one row coalesced (lane: 16 elems = 32B);
// per-lane qg segment in registers; 4-lane shfl reduce -> 16 head scores per row.
__global__ __launch_bounds__(256)
void rala_scores(const u16* __restrict__ K, const float* __restrict__ qg,
                 float* __restrict__ scores)
{
    int blk = blockIdx.x;              // 0..M_/64-1
    int row0 = blk * 64;
    int b = row0 >> 12;
    int tid = threadIdx.x;
    int lane = tid & 63, w = tid >> 6;
    float qr[16];
    const float qscale = 1.0f/(L_ * 8.0f);     // mean over L, / sqrt(D)=8
    #pragma unroll
    for (int j=0;j<16;++j) qr[j] = qg[b*E_ + lane*16 + j] * qscale;
    for (int it = 0; it < 16; ++it) {
        int r = row0 + w*16 + it;
        const u16* p = K + (size_t)r*E_ + lane*16;
        uint4 a0 = *(const uint4*)(p);
        uint4 a1 = *(const uint4*)(p + 8);
        const u16* u0 = (const u16*)&a0;
        const u16* u1 = (const u16*)&a1;
        float s = 0.f;
        #pragma unroll
        for (int j=0;j<8;++j) s = fmaf(bf2f(u0[j]), qr[j], s);
        #pragma unroll
        for (int j=0;j<8;++j) s = fmaf(bf2f(u1[j]), qr[8+j], s);
        s += __shfl_xor(s, 1);
        s += __shfl_xor(s, 2);
        if ((lane & 3) == 0) {
            int h = lane >> 2;
            int l = r & (L_-1);
            scores[((size_t)(b*H_ + h))*L_ + l] = s;
        }
    }
}

// ---------------- softmax over L+1 (zero token at 0) -> alpha ----------------
__global__ __launch_bounds__(256)
void rala_softmax(const float* __restrict__ scores, float* __restrict__ alpha)
{
    __shared__ float red[8];
    int bh = blockIdx.x, tid = threadIdx.x;
    const float* sc = scores + (size_t)bh*L_;
    float v[16];
    float mx = 0.f;                            // zero-token score = 0 included
    #pragma unroll
    for (int i=0;i<16;++i){ v[i] = sc[tid + i*256]; mx = fmaxf(mx, v[i]); }
    #pragma unroll
    for (int o=32;o;o>>=1) mx = fmaxf(mx, __shfl_xor(mx,o));
    int wv = tid >> 6;
    if ((tid & 63) == 0) red[wv] = mx;
    __syncthreads();
    mx = fmaxf(fmaxf(red[0],red[1]), fmaxf(red[2],red[3]));
    float sum = 0.f;
    #pragma unroll
    for (int i=0;i<16;++i){ v[i] = expf(v[i]-mx); sum += v[i]; }
    #pragma unroll
    for (int o=32;o;o>>=1) sum += __shfl_xor(sum,o);
    __syncthreads();
    if ((tid & 63) == 0) red[4+wv] = sum;
    __syncthreads();
    float Z = red[4]+red[5]+red[6]+red[7] + expf(-mx);
    float scale = (float)L_ / Z;
    float* al = alpha + (size_t)bh*LK_;
    #pragma unroll
    for (int i=0;i<16;++i) al[1 + tid + i*256] = v[i]*scale;
    if (tid==0) al[0] = expf(-mx)*scale;
}

// ---------------- KV[b,h,64,64] & Ksum[b,h,64] from scaled phiKs (bf16) & V (bf16) ----------------
#define NS_ 8
__global__ __launch_bounds__(256)
void kv_partial(const u16* __restrict__ phiKs, const u16* __restrict__ Vb,
                float* __restrict__ KV, float* __restrict__ Ksum)
{
    __shared__ float Ps[64][65];
    __shared__ float Vs[64][65];
    int blk = blockIdx.x;
    int s = blk & (NS_-1);
    int h = (blk >> 3) & 15;
    int b = blk >> 7;
    int tid = threadIdx.x;
    int tx = tid & 15, ty = tid >> 4;
    const size_t bh = (size_t)(b*H_ + h);
    float acc[4][4] = {};
    float ksl = 0.f;
    for (int ch = 0; ch < 8; ++ch) {
        int lbase = s*512 + ch*64;
        #pragma unroll
        for (int i=0;i<16;++i){
            int idx = tid + i*256;
            int r = idx >> 6, c2 = idx & 63;
            size_t g = ((size_t)b*L_ + lbase + r)*E_ + h*64 + c2;
            Ps[r][c2] = bf2f(phiKs[g]);
            Vs[r][c2] = bf2f(Vb[g]);
        }
        __syncthreads();
        #pragma unroll 8
        for (int l=0; l<64; ++l){
            float p[4], vv[4];
            #pragma unroll
            for (int i=0;i<4;++i) p[i] = Ps[l][ty*4+i];
            #pragma unroll
            for (int j=0;j<4;++j) vv[j] = Vs[l][tx*4+j];
            #pragma unroll
            for (int i=0;i<4;++i)
                #pragma unroll
                for (int j=0;j<4;++j)
                    acc[i][j] = fmaf(p[i], vv[j], acc[i][j]);
        }
        if (tid < 64){
            float t = 0.f;
            #pragma unroll 8
            for (int l=0; l<64; ++l) t += Ps[l][tid];
            ksl += t;
        }
        __syncthreads();
    }
    #pragma unroll
    for (int i=0;i<4;++i)
        #pragma unroll
        for (int j=0;j<4;++j)
            atomicAdd(&KV[(bh*D_ + ty*4+i)*D_ + tx*4+j], acc[i][j]);
    if (tid < 64) atomicAdd(&Ksum[bh*D_ + tid], ksl);
}

// zero-token: Ksum += (tanh(bphi_k)+1) * alpha0
__global__ void ksum_zero(const float* __restrict__ bphi_k,
                          const float* __restrict__ alpha, float* __restrict__ Ksum)
{
    int bh = blockIdx.x; int h = bh & 15; int d = threadIdx.x;
    float a0 = alpha[(size_t)bh*LK_];
    Ksum[(size_t)bh*D_ + d] += (tanhf(bphi_k[h*D_ + d]) + 1.0f) * a0;
}

// ---------------- attn = (phiQ @ KV) / (phiQ . Ksum + eps), bf16 out ----------------
__global__ __launch_bounds__(256)
void attn_core(const u16* __restrict__ phiQ, const float* __restrict__ KV,
               const float* __restrict__ Ksum, u16* __restrict__ attn)
{
    __shared__ float KVs[64][65];
    __shared__ float Ps[64][65];
    __shared__ float Ks_[64];
    int gid = blockIdx.x;
    int h = gid & 15; int rchunk = gid >> 4;
    int row0 = rchunk * 64;
    int b = row0 >> 12;
    const size_t bh = (size_t)(b*H_ + h);
    int tid = threadIdx.x;
    int tx = tid & 15, ty = tid >> 4;
    #pragma unroll
    for (int i=0;i<16;++i){
        int idx = tid + i*256;
        int r = idx >> 6, c2 = idx & 63;
        KVs[r][c2] = KV[bh*D_*D_ + r*64 + c2];
        Ps[r][c2]  = bf2f(phiQ[((size_t)row0 + r)*E_ + h*64 + c2]);
    }
    if (tid < 64) Ks_[tid] = Ksum[bh*D_ + tid];
    __syncthreads();
    float num[4][4] = {};
    float den[4] = {};
    for (int d=0; d<64; ++d){
        float kd = Ks_[d];
        float4 kv4 = *(const float4*)&KVs[d][tx*4];
        float kvv[4] = {kv4.x, kv4.y, kv4.z, kv4.w};
        #pragma unroll
        for (int i=0;i<4;++i){
            float q = Ps[ty*4+i][d];
            den[i] = fmaf(q, kd, den[i]);
            #pragma unroll
            for (int j=0;j<4;++j)
                num[i][j] = fmaf(q, kvv[j], num[i][j]);
        }
    }
    #pragma unroll
    for (int i=0;i<4;++i){
        float r = 1.0f / (den[i] + 1e-6f);
        #pragma unroll
        for (int j=0;j<4;++j)
            attn[((size_t)row0 + ty*4 + i)*E_ + h*64 + tx*4 + j] = f2bf(num[i][j] * r);
    }
}

// ---------------- grouped conv (k=5,pad=2,groups=H) + gated residual (bf16 io) ----------------
__global__ __launch_bounds__(256)
void conv_residual(const u16* __restrict__ attn, const float* __restrict__ conv_w,
                   const float* __restrict__ conv_b, const float* __restrict__ gamma_p,
                   u16* __restrict__ out)
{
    __shared__ float As_[68][65];
    __shared__ float Ws_[64][81];
    int blk = blockIdx.x;
    int lc = blk & 63; int h = (blk>>6) & 15; int b = blk >> 10;
    int tid = threadIdx.x;
    int tx = tid & 15, ty = tid >> 4;
    for (int i=tid; i<68*64; i+=256){
        int r = i>>6, cc = i&63;
        int l = lc*64 - 2 + r;
        As_[r][cc] = (l>=0 && l<L_) ? bf2f(attn[((size_t)b*L_+l)*E_ + h*D_ + cc]) : 0.f;
    }
    int e0 = tx*4, l0 = ty*4;
    float acc[4][4] = {};
    for (int dc=0; dc<4; ++dc){
        __syncthreads();
        for (int i=tid; i<64*80; i+=256){
            int ee = i/80, rem = i%80;
            Ws_[ee][rem] = conv_w[((size_t)(h*D_+ee))*320 + dc*80 + rem];
        }
        __syncthreads();
        #pragma unroll
        for (int dd=0; dd<16; ++dd){
            #pragma unroll
            for (int t=0; t<5; ++t){
                float wv[4], av[4];
                #pragma unroll
                for (int j=0;j<4;++j) wv[j] = Ws_[e0+j][dd*5+t];
                #pragma unroll
                for (int i=0;i<4;++i) av[i] = As_[l0+i+t][dc*16+dd];
                #pragma unroll
                for (int i=0;i<4;++i)
                    #pragma unroll
                    for (int j=0;j<4;++j)
                        acc[i][j] = fmaf(av[i], wv[j], acc[i][j]);
            }
        }
    }
    float gamma = *gamma_p;
    #pragma unroll
    for (int i=0;i<4;++i){
        int l = lc*64 + l0 + i;
        #pragma unroll
        for (int j=0;j<4;++j){
            int ee = e0 + j;
            float v = As_[l0+i+2][ee] + gamma*(acc[i][j] + conv_b[h*D_+ee]);
            out[((size_t)b*L_+l)*E_ + h*D_ + ee] = f2bf(v);
        }
    }
}

extern "C" void kernel_launch(void* const* d_in, const int* in_sizes, int n_in,
                              void* d_out, int out_size, void* d_ws, size_t ws_size,
                              hipStream_t stream)
{
    const float* x     = (const float*)d_in[0];
    const float* Wq    = (const float*)d_in[1];
    const float* bq    = (const float*)d_in[2];
    const float* lnq_g = (const float*)d_in[3];
    const float* lnq_b = (const float*)d_in[4];
    const float* Wk    = (const float*)d_in[5];
    const float* bk    = (const float*)d_in[6];
    const float* lnk_g = (const float*)d_in[7];
    const float* lnk_b = (const float*)d_in[8];
    const float* Wv    = (const float*)d_in[9];
    const float* bv    = (const float*)d_in[10];
    const float* lnv_g = (const float*)d_in[11];
    const float* lnv_b = (const float*)d_in[12];
    const float* Wphi_q= (const float*)d_in[13];
    const float* bphi_q= (const float*)d_in[14];
    const float* Wphi_k= (const float*)d_in[15];
    const float* bphi_k= (const float*)d_in[16];
    const float* lna_g = (const float*)d_in[17];
    const float* lna_b = (const float*)d_in[18];
    const float* W1    = (const float*)d_in[19];
    const float* b1    = (const float*)d_in[20];
    const float* W2    = (const float*)d_in[21];
    const float* b2    = (const float*)d_in[22];
    const float* gamma = (const float*)d_in[23];
    const float* conv_w= (const float*)d_in[24];
    const float* conv_b= (const float*)d_in[25];
    float* out = (float*)d_out;

    // ---- workspace layout (bytes) ----
    char* base = (char*)d_ws;
    const size_t WT_SQ = (size_t)E_*E_*2;            // 2 MiB each
    const size_t WT_ALL = 5*WT_SQ + 2*(size_t)E_*MLP_*2;
    const size_t BUF = (size_t)M_*E_*2;              // 32 MiB bf16 buffer
    u16* Wqt  = (u16*)base;
    u16* Wkt  = (u16*)(base + 1*WT_SQ);
    u16* Wvt  = (u16*)(base + 2*WT_SQ);
    u16* Wqpt = (u16*)(base + 3*WT_SQ);
    u16* Wkpt = (u16*)(base + 4*WT_SQ);
    u16* W1t  = (u16*)(base + 5*WT_SQ);                       // [4096,1024]
    u16* W2t  = (u16*)(base + 5*WT_SQ + (size_t)E_*MLP_*2);   // [1024,4096]
    char* bufs = base + WT_ALL;
    u16* xb = (u16*)(bufs);            // x bf16 / phiKs / aln_b
    u16* Qb = (u16*)(bufs + 1*BUF);    // Q / attn2_b / h1
    u16* Kb = (u16*)(bufs + 2*BUF);    // K / attn_b / aln_f(lo half)
    u16* Vb = (u16*)(bufs + 3*BUF);    // V / phiQ / aln_f(hi half)
    char* small = bufs + 4*BUF;
    float* qg     = (float*)small;                      // B*E
    float* alpha  = qg + B_*E_;                         // B*H*LK
    float* KV     = alpha + (size_t)B_*H_*LK_;          // B*H*D*D
    float* Ksum   = KV + (size_t)B_*H_*D_*D_;           // B*H*D
    float* scores = Ksum + (size_t)B_*H_*D_;            // B*H*L
    const size_t need = WT_ALL + 4*BUF +
        ((size_t)B_*E_ + (size_t)B_*H_*LK_ + (size_t)B_*H_*D_*D_ + (size_t)B_*H_*D_
         + (size_t)B_*H_*L_)*4;
    if (ws_size < need) return;    // fail visibly rather than fault

    u16* phiKs = xb;                 // after QKV GEMMs, xb is dead
    u16* phiQ  = Vb;                 // after kv_partial, Vb is dead
    u16* attn_b  = Kb;               // after scores+phiK gemm, Kb dead
    u16* attn2_b = Qb;               // after phiQ gemm, Qb dead
    float* aln_f = (float*)Kb;       // 64 MiB spanning Kb+Vb
    u16* aln_b   = xb;
    u16* h1      = Qb;

    dim3 blk256(256);
    // weight conversions (transpose to [N,K] bf16)
    wcvt<<<dim3(32,32),  blk256, 0, stream>>>(Wq, Wqt, E_, E_);
    wcvt<<<dim3(32,32),  blk256, 0, stream>>>(Wk, Wkt, E_, E_);
    wcvt<<<dim3(32,32),  blk256, 0, stream>>>(Wv, Wvt, E_, E_);
    wcvt<<<dim3(32,32),  blk256, 0, stream>>>(Wphi_q, Wqpt, E_, E_);
    wcvt<<<dim3(32,32),  blk256, 0, stream>>>(Wphi_k, Wkpt, E_, E_);
    wcvt<<<dim3(128,32), blk256, 0, stream>>>(W1, W1t, E_, MLP_);
    wcvt<<<dim3(32,128), blk256, 0, stream>>>(W2, W2t, MLP_, E_);
    xcvt<<<M_*E_/1024, blk256, 0, stream>>>(x, xb);
    // QKV projections (bf16 out) + LN in place
    hipLaunchKernelGGL((gemm_bf16<0>), dim3(8,128), blk256, 0, stream, xb, Wqt, bq, Qb, M_, E_, E_, nullptr, nullptr);
    hipLaunchKernelGGL((gemm_bf16<0>), dim3(8,128), blk256, 0, stream, xb, Wkt, bk, Kb, M_, E_, E_, nullptr, nullptr);
    hipLaunchKernelGGL((gemm_bf16<0>), dim3(8,128), blk256, 0, stream, xb, Wvt, bv, Vb, M_, E_, E_, nullptr, nullptr);
    ln_bf16<<<M_, 256, 0, stream>>>(Qb, lnq_g, lnq_b);
    ln_bf16<<<M_, 256, 0, stream>>>(Kb, lnk_g, lnk_b);
    ln_bf16<<<M_, 256, 0, stream>>>(Vb, lnv_g, lnv_b);
    // qg and alpha (parallelized scores + small softmax)
    hipMemsetAsync(qg, 0, B_*E_*sizeof(float), stream);
    qg_partial<<<B_*64, 1024, 0, stream>>>(Qb, qg);
    rala_scores<<<M_/64, 256, 0, stream>>>(Kb, qg, scores);
    rala_softmax<<<B_*H_, 256, 0, stream>>>(scores, alpha);
    // phiK (alpha folded) -> phiKs (= xb region)
    hipLaunchKernelGGL((gemm_bf16<2>), dim3(8,128), blk256, 0, stream, Kb, Wkpt, bphi_k, phiKs, M_, E_, E_, alpha, nullptr);
    // KV / Ksum
    hipMemsetAsync(KV,   0, (size_t)B_*H_*D_*D_*sizeof(float), stream);
    hipMemsetAsync(Ksum, 0, (size_t)B_*H_*D_*sizeof(float), stream);
    kv_partial<<<B_*H_*NS_, 256, 0, stream>>>(phiKs, Vb, KV, Ksum);
    ksum_zero<<<B_*H_, 64, 0, stream>>>(bphi_k, alpha, Ksum);
    // phiQ (= Vb region, V dead after kv_partial)
    hipLaunchKernelGGL((gemm_bf16<1>), dim3(8,128), blk256, 0, stream, Qb, Wqpt, bphi_q, phiQ, M_, E_, E_, nullptr, nullptr);
    // attention output -> attn_b (= Kb region)
    attn_core<<<(M_/64)*H_, 256, 0, stream>>>(phiQ, KV, Ksum, attn_b);
    // conv + gated residual -> attn2_b (= Qb region)
    conv_residual<<<B_*H_*64, 256, 0, stream>>>(attn_b, conv_w, conv_b, gamma, attn2_b);
    // final LN: f32 copy (Kb+Vb) + bf16 copy (xb)
    ln_dual<<<M_, 256, 0, stream>>>(attn2_b, lna_g, lna_b, aln_f, aln_b);
    // MLP + residuals, 4 chunks of 4096 rows; hidden h1 in Qb region
    for (int c=0; c<4; ++c){
        const u16* Ain   = aln_b + (size_t)c*4096*E_;
        const float* Rf  = aln_f + (size_t)c*4096*E_;
        const float* xin = x     + (size_t)c*4096*E_;
        float* outc = out + (size_t)c*4096*E_;
        hipLaunchKernelGGL((gemm_bf16<3>), dim3(32,32), blk256, 0, stream, Ain, W1t, b1, h1, 4096, MLP_, E_, nullptr, nullptr);
        hipLaunchKernelGGL((gemm_bf16<4>), dim3(8,32),  blk256, 0, stream, h1, W2t, b2, outc, 4096, E_, MLP_, Rf, xin);
    }
}